// Round 5
// baseline (1888.812 us; speedup 1.0000x reference)
//
#include <hip/hip_runtime.h>
#include <cstdint>
#include <cstddef>

#define D_MODEL 768
#define D_SAE   6144
#define KTOP    32
#define BATCH   8192

// d_out layout (floats): x_hat [8192*768] | latents [8192*6144] | loss | aux_loss
#define XHAT_OFF   ((size_t)0)
#define LAT_OFF    ((size_t)BATCH * D_MODEL)
#define LOSS_OFF   (LAT_OFF + (size_t)BATCH * D_SAE)

// ---------------- init loss slots ----------------
__global__ void init_loss(float* lossp) {
    if (threadIdx.x < 2) lossp[threadIdx.x] = 0.0f;
}

// ---------------- W_dec row inverse norms -> stash in xhat region head ----------------
__global__ __launch_bounds__(256) void rownorm_kernel(const float* __restrict__ Wdec,
                                                      float* __restrict__ invn) {
    int j = blockIdx.x;
    int t = threadIdx.x;
    const float* src = Wdec + (size_t)j * D_MODEL;
    float ss = 0.f;
    for (int c = t; c < D_MODEL; c += 256) { float v = src[c]; ss += v * v; }
    #pragma unroll
    for (int m = 32; m >= 1; m >>= 1) ss += __shfl_xor(ss, m, 64);
    __shared__ float wsum[4];
    int wid = t >> 6, lane = t & 63;
    if (lane == 0) wsum[wid] = ss;
    __syncthreads();
    if (t == 0) {
        float s = wsum[0] + wsum[1] + wsum[2] + wsum[3];
        invn[j] = 1.0f / fmaxf(sqrtf(s), 1e-12f);
    }
}

// ---------------- pre_acts GEMM: C = x @ W_enc + b_enc ----------------
// fp32 single ascending-k FMA chain per output element (BLAS microkernel semantics):
// near-tie rounding then matches the np/jax fp32 reference, so top-k ranking agrees.
#define BM 64
#define BN 64
#define BK 16

__global__ __launch_bounds__(256) void gemm_preacts(const float* __restrict__ X,
                                                    const float* __restrict__ W,
                                                    const float* __restrict__ be,
                                                    float* __restrict__ C) {
    __shared__ float As[BK][BM + 4];
    __shared__ float Bs[BK][BN];

    int tid = threadIdx.x;
    int tx = tid & 15, ty = tid >> 4;
    int m0 = blockIdx.y * BM, n0 = blockIdx.x * BN;

    int ar = tid >> 2;          // 0..63 (m row)
    int ac = (tid & 3) * 4;     // k offset
    int bkr = tid >> 4;         // 0..15 (k row)
    int bc = (tid & 15) * 4;    // n offset

    float cacc[4][4];
    #pragma unroll
    for (int i = 0; i < 4; ++i)
        #pragma unroll
        for (int j = 0; j < 4; ++j) cacc[i][j] = 0.0f;

    for (int k0 = 0; k0 < 768; k0 += BK) {
        float4 av = *reinterpret_cast<const float4*>(X + (size_t)(m0 + ar) * 768 + k0 + ac);
        As[ac + 0][ar] = av.x;
        As[ac + 1][ar] = av.y;
        As[ac + 2][ar] = av.z;
        As[ac + 3][ar] = av.w;
        *reinterpret_cast<float4*>(&Bs[bkr][bc]) =
            *reinterpret_cast<const float4*>(W + (size_t)(k0 + bkr) * D_SAE + n0 + bc);
        __syncthreads();

        #pragma unroll
        for (int kk = 0; kk < BK; ++kk) {
            float4 a = *reinterpret_cast<const float4*>(&As[kk][ty * 4]);
            float4 b = *reinterpret_cast<const float4*>(&Bs[kk][tx * 4]);
            float aa[4] = {a.x, a.y, a.z, a.w};
            float bb[4] = {b.x, b.y, b.z, b.w};
            #pragma unroll
            for (int i = 0; i < 4; ++i)
                #pragma unroll
                for (int j = 0; j < 4; ++j)
                    cacc[i][j] = fmaf(aa[i], bb[j], cacc[i][j]);
        }
        __syncthreads();
    }

    float4 be4 = *reinterpret_cast<const float4*>(be + n0 + tx * 4);
    float bbias[4] = {be4.x, be4.y, be4.z, be4.w};
    #pragma unroll
    for (int i = 0; i < 4; ++i) {
        int row = m0 + ty * 4 + i;
        float4 o;
        o.x = cacc[i][0] + bbias[0];
        o.y = cacc[i][1] + bbias[1];
        o.z = cacc[i][2] + bbias[2];
        o.w = cacc[i][3] + bbias[3];
        *reinterpret_cast<float4*>(C + (size_t)row * D_SAE + n0 + tx * 4) = o;
    }
}

// ---------------- top-64 selection on stored fp32 pre_acts + header stash ----------------
__global__ __launch_bounds__(256) void select_kernel(const float* __restrict__ invn,
                                                     float* __restrict__ lat) {
    __shared__ float row[D_SAE];
    __shared__ float wv[4];
    __shared__ int wi[4];
    __shared__ float sv[64];
    __shared__ int si[64];

    int r = blockIdx.x, t = threadIdx.x;
    int lane = t & 63, wid = t >> 6;
    float* L = lat + (size_t)r * D_SAE;

    for (int i = t; i < D_SAE; i += 256) row[i] = L[i];
    __syncthreads();

    for (int sel = 0; sel < 64; ++sel) {
        float bv = -3.0e38f;
        int bi = D_SAE;
        for (int i = t; i < D_SAE; i += 256) {
            float v = row[i];
            if (v > bv) { bv = v; bi = i; }  // ascending scan: smallest index on ties
        }
        #pragma unroll
        for (int m = 1; m < 64; m <<= 1) {
            float ov = __shfl_xor(bv, m, 64);
            int oi = __shfl_xor(bi, m, 64);
            if (ov > bv || (ov == bv && oi < bi)) { bv = ov; bi = oi; }
        }
        if (lane == 0) { wv[wid] = bv; wi[wid] = bi; }
        __syncthreads();
        if (t == 0) {
            float fv = wv[0]; int fi = wi[0];
            #pragma unroll
            for (int w = 1; w < 4; ++w)
                if (wv[w] > fv || (wv[w] == fv && wi[w] < fi)) { fv = wv[w]; fi = wi[w]; }
            sv[sel] = fv; si[sel] = fi;
            row[fi] = -3.0e38f;
        }
        __syncthreads();
        if (sel == 31) {
            // mask = (latents > 0): non-positive top-32 keep pre value in masked_pre_acts
            if (t < 32) {
                float v = sv[t];
                if (v <= 0.0f) row[si[t]] = v;
            }
            __syncthreads();
        }
    }

    // header stash into the latents row (decode kernel consumes & overwrites):
    // [0,64): selected indices (int bits); [64,96): relu(main vals); [96,160): decode scales
    if (t < 64) {
        L[t] = __int_as_float(si[t]);
    } else if (t < 96) {
        L[t] = fmaxf(sv[t - 64], 0.0f);
    } else if (t < 160) {
        int j = t - 96;
        L[t] = fmaxf(sv[j], 0.0f) * invn[si[j]];
    }
}

// ---------------- latents write + decode + losses ----------------
__global__ __launch_bounds__(256) void decode_kernel(const float* __restrict__ X,
                                                     const float* __restrict__ Wdec,
                                                     const float* __restrict__ bdec,
                                                     float* __restrict__ lat,
                                                     float* __restrict__ xhat,
                                                     float* __restrict__ lossp) {
    __shared__ int sib[64];
    __shared__ float lv[32];
    __shared__ float sc[64];

    int r = blockIdx.x, t = threadIdx.x;
    int lane = t & 63, wid = t >> 6;
    float* L = lat + (size_t)r * D_SAE;

    if (t < 64) sib[t] = __float_as_int(L[t]);
    else if (t < 96) lv[t - 64] = L[t];
    else if (t < 160) sc[t - 96] = L[t];
    __syncthreads();

    for (int i = t; i < D_SAE; i += 256) L[i] = 0.0f;
    __syncthreads();
    if (t < 32) L[sib[t]] = lv[t];

    int c0 = t, c1 = t + 256, c2 = t + 512;
    float xh0 = bdec[c0], xh1 = bdec[c1], xh2 = bdec[c2];
    #pragma unroll 4
    for (int j = 0; j < 32; ++j) {
        const float* w = Wdec + (size_t)sib[j] * D_MODEL;
        float v = sc[j];
        xh0 += v * w[c0]; xh1 += v * w[c1]; xh2 += v * w[c2];
    }
    float a0 = 0.f, a1 = 0.f, a2 = 0.f;
    #pragma unroll 4
    for (int j = 32; j < 64; ++j) {
        const float* w = Wdec + (size_t)sib[j] * D_MODEL;
        float v = sc[j];
        a0 += v * w[c0]; a1 += v * w[c1]; a2 += v * w[c2];
    }
    const float* xr = X + (size_t)r * D_MODEL;
    float xv0 = xr[c0], xv1 = xr[c1], xv2 = xr[c2];
    float* xo = xhat + (size_t)r * D_MODEL;
    xo[c0] = xh0; xo[c1] = xh1; xo[c2] = xh2;

    float d0 = xh0 - xv0, d1 = xh1 - xv1, d2 = xh2 - xv2;
    float lsum = d0 * d0 + d1 * d1 + d2 * d2;
    float e0 = a0 - (xv0 - xh0), e1 = a1 - (xv1 - xh1), e2 = a2 - (xv2 - xh2);
    float asum = e0 * e0 + e1 * e1 + e2 * e2;

    #pragma unroll
    for (int m = 32; m >= 1; m >>= 1) {
        lsum += __shfl_xor(lsum, m, 64);
        asum += __shfl_xor(asum, m, 64);
    }
    __shared__ float rl[4], ra[4];
    if (lane == 0) { rl[wid] = lsum; ra[wid] = asum; }
    __syncthreads();
    if (t == 0) {
        atomicAdd(&lossp[0], rl[0] + rl[1] + rl[2] + rl[3]);
        atomicAdd(&lossp[1], ra[0] + ra[1] + ra[2] + ra[3]);
    }
}

// ---------------- final scalars ----------------
__global__ void finish_kernel(float* __restrict__ lossp) {
    const double inv = 1.0 / (double)((size_t)BATCH * D_MODEL);
    if (threadIdx.x == 0) {
        lossp[0] = (float)((double)lossp[0] * inv);
        lossp[1] = (float)((double)lossp[1] * inv * (1.0 / 32.0));
    }
}

extern "C" void kernel_launch(void* const* d_in, const int* in_sizes, int n_in,
                              void* d_out, int out_size, void* d_ws, size_t ws_size,
                              hipStream_t stream) {
    const float* x     = (const float*)d_in[0];
    const float* W_enc = (const float*)d_in[1];
    const float* b_enc = (const float*)d_in[2];
    const float* W_dec = (const float*)d_in[3];
    const float* b_dec = (const float*)d_in[4];

    float* out = (float*)d_out;
    float* xhat  = out + XHAT_OFF;
    float* lat   = out + LAT_OFF;
    float* lossp = out + LOSS_OFF;
    float* invn  = xhat;   // first 6144 floats of xhat region; consumed before xhat write

    hipLaunchKernelGGL(init_loss, dim3(1), dim3(64), 0, stream, lossp);
    hipLaunchKernelGGL(rownorm_kernel, dim3(D_SAE), dim3(256), 0, stream, W_dec, invn);
    hipLaunchKernelGGL(gemm_preacts, dim3(D_SAE / BN, BATCH / BM), dim3(256), 0, stream,
                       x, W_enc, b_enc, lat);
    hipLaunchKernelGGL(select_kernel, dim3(BATCH), dim3(256), 0, stream, invn, lat);
    hipLaunchKernelGGL(decode_kernel, dim3(BATCH), dim3(256), 0, stream,
                       x, W_dec, b_dec, lat, xhat, lossp);
    hipLaunchKernelGGL(finish_kernel, dim3(1), dim3(1), 0, stream, lossp);
}

// Round 6
// 1559.907 us; speedup vs baseline: 1.2108x; 1.2108x over previous
//
#include <hip/hip_runtime.h>
#include <cstdint>
#include <cstddef>

#define D_MODEL 768
#define D_SAE   6144
#define KTOP    32
#define BATCH   8192

// d_out layout (floats): x_hat [8192*768] | latents [8192*6144] | loss | aux_loss
#define XHAT_OFF   ((size_t)0)
#define LAT_OFF    ((size_t)BATCH * D_MODEL)
#define LOSS_OFF   (LAT_OFF + (size_t)BATCH * D_SAE)

#define NCAP 128   // candidate slots for sort (top-64 + ties)

// ---------------- init loss slots ----------------
__global__ void init_loss(float* lossp) {
    if (threadIdx.x < 2) lossp[threadIdx.x] = 0.0f;
}

// ---------------- W_dec row inverse norms -> stash in xhat region head ----------------
__global__ __launch_bounds__(256) void rownorm_kernel(const float* __restrict__ Wdec,
                                                      float* __restrict__ invn) {
    int j = blockIdx.x;
    int t = threadIdx.x;
    const float* src = Wdec + (size_t)j * D_MODEL;
    float ss = 0.f;
    for (int c = t; c < D_MODEL; c += 256) { float v = src[c]; ss += v * v; }
    #pragma unroll
    for (int m = 32; m >= 1; m >>= 1) ss += __shfl_xor(ss, m, 64);
    __shared__ float wsum[4];
    int wid = t >> 6, lane = t & 63;
    if (lane == 0) wsum[wid] = ss;
    __syncthreads();
    if (t == 0) {
        float s = wsum[0] + wsum[1] + wsum[2] + wsum[3];
        invn[j] = 1.0f / fmaxf(sqrtf(s), 1e-12f);
    }
}

// ---------------- pre_acts GEMM: C = x @ W_enc + b_enc ----------------
// 128x128 tile, 8x8 per thread. Each C element keeps ONE fp32 accumulator with an
// ascending-k fmaf chain (BLAS microkernel semantics) so near-tie rounding matches
// the fp32 reference and the top-k ranking agrees. Do not reassociate.
#define BM 128
#define BN 128
#define BK 16

__global__ __launch_bounds__(256) void gemm_preacts(const float* __restrict__ X,
                                                    const float* __restrict__ W,
                                                    const float* __restrict__ be,
                                                    float* __restrict__ C) {
    __shared__ float As[BK][BM + 4];  // k-major, m contiguous
    __shared__ float Bs[BK][BN];

    int tid = threadIdx.x;
    int tx = tid & 15, ty = tid >> 4;      // 16x16 thread grid, 8x8 each
    int m0 = blockIdx.y * BM, n0 = blockIdx.x * BN;

    // A staging: rows ar and ar+64, k-offset ac (float4) -> 64B segments per 4 lanes
    int ar = tid >> 2;          // 0..63
    int ac = (tid & 3) * 4;     // 0,4,8,12
    // B staging: row bkr, cols bc..bc+7 -> 512B contiguous per 16 lanes
    int bkr = tid >> 4;         // 0..15
    int bc = (tid & 15) * 8;    // 0..120

    float acc[8][8];
    #pragma unroll
    for (int i = 0; i < 8; ++i)
        #pragma unroll
        for (int j = 0; j < 8; ++j) acc[i][j] = 0.0f;

    for (int k0 = 0; k0 < 768; k0 += BK) {
        float4 av1 = *reinterpret_cast<const float4*>(X + (size_t)(m0 + ar) * 768 + k0 + ac);
        float4 av2 = *reinterpret_cast<const float4*>(X + (size_t)(m0 + 64 + ar) * 768 + k0 + ac);
        As[ac + 0][ar] = av1.x;  As[ac + 1][ar] = av1.y;
        As[ac + 2][ar] = av1.z;  As[ac + 3][ar] = av1.w;
        As[ac + 0][64 + ar] = av2.x;  As[ac + 1][64 + ar] = av2.y;
        As[ac + 2][64 + ar] = av2.z;  As[ac + 3][64 + ar] = av2.w;
        float4 bv1 = *reinterpret_cast<const float4*>(W + (size_t)(k0 + bkr) * D_SAE + n0 + bc);
        float4 bv2 = *reinterpret_cast<const float4*>(W + (size_t)(k0 + bkr) * D_SAE + n0 + bc + 4);
        *reinterpret_cast<float4*>(&Bs[bkr][bc])     = bv1;
        *reinterpret_cast<float4*>(&Bs[bkr][bc + 4]) = bv2;
        __syncthreads();

        #pragma unroll
        for (int kk = 0; kk < BK; ++kk) {
            float4 a0 = *reinterpret_cast<const float4*>(&As[kk][ty * 8]);
            float4 a1 = *reinterpret_cast<const float4*>(&As[kk][ty * 8 + 4]);
            float4 b0 = *reinterpret_cast<const float4*>(&Bs[kk][tx * 8]);
            float4 b1 = *reinterpret_cast<const float4*>(&Bs[kk][tx * 8 + 4]);
            float aa[8] = {a0.x, a0.y, a0.z, a0.w, a1.x, a1.y, a1.z, a1.w};
            float bb[8] = {b0.x, b0.y, b0.z, b0.w, b1.x, b1.y, b1.z, b1.w};
            #pragma unroll
            for (int i = 0; i < 8; ++i)
                #pragma unroll
                for (int j = 0; j < 8; ++j)
                    acc[i][j] = fmaf(aa[i], bb[j], acc[i][j]);
        }
        __syncthreads();
    }

    float4 be0 = *reinterpret_cast<const float4*>(be + n0 + tx * 8);
    float4 be1 = *reinterpret_cast<const float4*>(be + n0 + tx * 8 + 4);
    float bbias[8] = {be0.x, be0.y, be0.z, be0.w, be1.x, be1.y, be1.z, be1.w};
    #pragma unroll
    for (int i = 0; i < 8; ++i) {
        size_t row = (size_t)(m0 + ty * 8 + i);
        float4 o0, o1;
        o0.x = acc[i][0] + bbias[0]; o0.y = acc[i][1] + bbias[1];
        o0.z = acc[i][2] + bbias[2]; o0.w = acc[i][3] + bbias[3];
        o1.x = acc[i][4] + bbias[4]; o1.y = acc[i][5] + bbias[5];
        o1.z = acc[i][6] + bbias[6]; o1.w = acc[i][7] + bbias[7];
        *reinterpret_cast<float4*>(C + row * D_SAE + n0 + tx * 8)     = o0;
        *reinterpret_cast<float4*>(C + row * D_SAE + n0 + tx * 8 + 4) = o1;
    }
}

// ---------------- exact top-64 via radix select + bitonic sort + header stash --------
__device__ inline unsigned int f2key(float f) {
    unsigned int u = __float_as_uint(f);
    return (u & 0x80000000u) ? ~u : (u | 0x80000000u);   // ascending uint == ascending float
}
__device__ inline float key2f(unsigned int u) {
    return (u & 0x80000000u) ? __uint_as_float(u & 0x7FFFFFFFu) : __uint_as_float(~u);
}

__global__ __launch_bounds__(256) void select_kernel(const float* __restrict__ invn,
                                                     float* __restrict__ lat) {
    __shared__ unsigned int us[D_SAE];
    __shared__ unsigned int hist[256];
    __shared__ unsigned long long skey[NCAP];
    __shared__ unsigned int prefix_s;
    __shared__ int rank_s, ncand_s;
    __shared__ float sv[64];
    __shared__ int si[64];

    int r = blockIdx.x, t = threadIdx.x;
    float* L = lat + (size_t)r * D_SAE;

    for (int i = t; i < D_SAE; i += 256) us[i] = f2key(L[i]);
    if (t == 0) { prefix_s = 0; rank_s = 64; ncand_s = 0; }
    __syncthreads();

    // ---- 4-pass radix select: exact 64th-largest key ----
    #pragma unroll
    for (int pass = 0; pass < 4; ++pass) {
        int shift = 24 - pass * 8;
        hist[t] = 0;
        __syncthreads();
        unsigned int pfx = prefix_s;
        for (int i = t; i < D_SAE; i += 256) {
            unsigned int u = us[i];
            bool in_group = (pass == 0) || ((u >> (shift + 8)) == pfx);
            if (in_group) atomicAdd(&hist[(u >> shift) & 255u], 1u);
        }
        __syncthreads();
        if (t == 0) {
            int rank = rank_s;
            unsigned int c = 0;
            for (int b = 255; b >= 0; --b) {
                unsigned int nc = c + hist[b];
                if ((int)nc >= rank) {
                    prefix_s = (prefix_s << 8) | (unsigned int)b;
                    rank_s = rank - (int)c;
                    break;
                }
                c = nc;
            }
        }
        __syncthreads();
    }
    unsigned int utau = prefix_s;   // key of the 64th-largest value

    // ---- gather all candidates >= utau ----
    for (int i = t; i < D_SAE; i += 256) {
        unsigned int u = us[i];
        if (u >= utau) {
            int p = atomicAdd(&ncand_s, 1);
            if (p < NCAP) skey[p] = (((unsigned long long)(~u)) << 32) | (unsigned int)i;
        }
    }
    __syncthreads();
    int n = ncand_s < NCAP ? ncand_s : NCAP;
    for (int p = n + t; p < NCAP; p += 256) skey[p] = 0xFFFFFFFFFFFFFFFFULL;
    __syncthreads();

    // ---- bitonic sort 128 slots ascending: (value desc, index asc) ----
    for (int k = 2; k <= NCAP; k <<= 1) {
        for (int j = k >> 1; j > 0; j >>= 1) {
            if (t < NCAP) {
                int ixj = t ^ j;
                if (ixj > t) {
                    unsigned long long a = skey[t], b = skey[ixj];
                    bool up = ((t & k) == 0);
                    if (up ? (a > b) : (a < b)) { skey[t] = b; skey[ixj] = a; }
                }
            }
            __syncthreads();
        }
    }

    // ---- main-32 + aux-32 (aux skips positive mains, re-admits non-positive mains) ----
    if (t == 0) {
        for (int j = 0; j < 32; ++j) {
            unsigned int u = ~(unsigned int)(skey[j] >> 32);
            si[j] = (int)(unsigned int)skey[j];
            sv[j] = key2f(u);
        }
        int cnt = 0;
        for (int c = 0; c < n && cnt < 32; ++c) {
            unsigned int u = ~(unsigned int)(skey[c] >> 32);
            float v = key2f(u);
            bool posmain = (c < 32) && (v > 0.0f);
            if (!posmain) {
                si[32 + cnt] = (int)(unsigned int)skey[c];
                sv[32 + cnt] = v;
                ++cnt;
            }
        }
    }
    __syncthreads();

    // header stash into the latents row (decode consumes & overwrites):
    // [0,64): indices (int bits); [64,96): relu(main vals); [96,160): decode scales
    if (t < 64) {
        L[t] = __int_as_float(si[t]);
    } else if (t < 96) {
        L[t] = fmaxf(sv[t - 64], 0.0f);
    } else if (t < 160) {
        int j = t - 96;
        L[t] = fmaxf(sv[j], 0.0f) * invn[si[j]];
    }
}

// ---------------- latents write + decode + losses ----------------
__global__ __launch_bounds__(256) void decode_kernel(const float* __restrict__ X,
                                                     const float* __restrict__ Wdec,
                                                     const float* __restrict__ bdec,
                                                     float* __restrict__ lat,
                                                     float* __restrict__ xhat,
                                                     float* __restrict__ lossp) {
    __shared__ int sib[64];
    __shared__ float lv[32];
    __shared__ float sc[64];

    int r = blockIdx.x, t = threadIdx.x;
    int lane = t & 63, wid = t >> 6;
    float* L = lat + (size_t)r * D_SAE;

    if (t < 64) sib[t] = __float_as_int(L[t]);
    else if (t < 96) lv[t - 64] = L[t];
    else if (t < 160) sc[t - 96] = L[t];
    __syncthreads();

    for (int i = t; i < D_SAE; i += 256) L[i] = 0.0f;
    __syncthreads();
    if (t < 32) L[sib[t]] = lv[t];

    int c0 = t, c1 = t + 256, c2 = t + 512;
    float xh0 = bdec[c0], xh1 = bdec[c1], xh2 = bdec[c2];
    #pragma unroll 4
    for (int j = 0; j < 32; ++j) {
        const float* w = Wdec + (size_t)sib[j] * D_MODEL;
        float v = sc[j];
        xh0 += v * w[c0]; xh1 += v * w[c1]; xh2 += v * w[c2];
    }
    float a0 = 0.f, a1 = 0.f, a2 = 0.f;
    #pragma unroll 4
    for (int j = 32; j < 64; ++j) {
        const float* w = Wdec + (size_t)sib[j] * D_MODEL;
        float v = sc[j];
        a0 += v * w[c0]; a1 += v * w[c1]; a2 += v * w[c2];
    }
    const float* xr = X + (size_t)r * D_MODEL;
    float xv0 = xr[c0], xv1 = xr[c1], xv2 = xr[c2];
    float* xo = xhat + (size_t)r * D_MODEL;
    xo[c0] = xh0; xo[c1] = xh1; xo[c2] = xh2;

    float d0 = xh0 - xv0, d1 = xh1 - xv1, d2 = xh2 - xv2;
    float lsum = d0 * d0 + d1 * d1 + d2 * d2;
    float e0 = a0 - (xv0 - xh0), e1 = a1 - (xv1 - xh1), e2 = a2 - (xv2 - xh2);
    float asum = e0 * e0 + e1 * e1 + e2 * e2;

    #pragma unroll
    for (int m = 32; m >= 1; m >>= 1) {
        lsum += __shfl_xor(lsum, m, 64);
        asum += __shfl_xor(asum, m, 64);
    }
    __shared__ float rl[4], ra[4];
    if (lane == 0) { rl[wid] = lsum; ra[wid] = asum; }
    __syncthreads();
    if (t == 0) {
        atomicAdd(&lossp[0], rl[0] + rl[1] + rl[2] + rl[3]);
        atomicAdd(&lossp[1], ra[0] + ra[1] + ra[2] + ra[3]);
    }
}

// ---------------- final scalars ----------------
__global__ void finish_kernel(float* __restrict__ lossp) {
    const double inv = 1.0 / (double)((size_t)BATCH * D_MODEL);
    if (threadIdx.x == 0) {
        lossp[0] = (float)((double)lossp[0] * inv);
        lossp[1] = (float)((double)lossp[1] * inv * (1.0 / 32.0));
    }
}

extern "C" void kernel_launch(void* const* d_in, const int* in_sizes, int n_in,
                              void* d_out, int out_size, void* d_ws, size_t ws_size,
                              hipStream_t stream) {
    const float* x     = (const float*)d_in[0];
    const float* W_enc = (const float*)d_in[1];
    const float* b_enc = (const float*)d_in[2];
    const float* W_dec = (const float*)d_in[3];
    const float* b_dec = (const float*)d_in[4];

    float* out = (float*)d_out;
    float* xhat  = out + XHAT_OFF;
    float* lat   = out + LAT_OFF;
    float* lossp = out + LOSS_OFF;
    float* invn  = xhat;   // first 6144 floats of xhat region; consumed before xhat write

    hipLaunchKernelGGL(init_loss, dim3(1), dim3(64), 0, stream, lossp);
    hipLaunchKernelGGL(rownorm_kernel, dim3(D_SAE), dim3(256), 0, stream, W_dec, invn);
    hipLaunchKernelGGL(gemm_preacts, dim3(D_SAE / BN, BATCH / BM), dim3(256), 0, stream,
                       x, W_enc, b_enc, lat);
    hipLaunchKernelGGL(select_kernel, dim3(BATCH), dim3(256), 0, stream, invn, lat);
    hipLaunchKernelGGL(decode_kernel, dim3(BATCH), dim3(256), 0, stream,
                       x, W_dec, b_dec, lat, xhat, lossp);
    hipLaunchKernelGGL(finish_kernel, dim3(1), dim3(1), 0, stream, lossp);
}

// Round 7
// 1550.967 us; speedup vs baseline: 1.2178x; 1.0058x over previous
//
#include <hip/hip_runtime.h>
#include <cstdint>
#include <cstddef>

#define D_MODEL 768
#define D_SAE   6144
#define KTOP    32
#define BATCH   8192

// d_out layout (floats): x_hat [8192*768] | latents [8192*6144] | loss | aux_loss
#define XHAT_OFF   ((size_t)0)
#define LAT_OFF    ((size_t)BATCH * D_MODEL)
#define LOSS_OFF   (LAT_OFF + (size_t)BATCH * D_SAE)

#define NCAP 128   // candidate slots for sort (top-64 + ties)

// ---------------- init loss slots ----------------
__global__ void init_loss(float* lossp) {
    if (threadIdx.x < 2) lossp[threadIdx.x] = 0.0f;
}

// ---------------- W_dec row inverse norms -> stash in xhat region head ----------------
__global__ __launch_bounds__(256) void rownorm_kernel(const float* __restrict__ Wdec,
                                                      float* __restrict__ invn) {
    int j = blockIdx.x;
    int t = threadIdx.x;
    const float* src = Wdec + (size_t)j * D_MODEL;
    float ss = 0.f;
    for (int c = t; c < D_MODEL; c += 256) { float v = src[c]; ss += v * v; }
    #pragma unroll
    for (int m = 32; m >= 1; m >>= 1) ss += __shfl_xor(ss, m, 64);
    __shared__ float wsum[4];
    int wid = t >> 6, lane = t & 63;
    if (lane == 0) wsum[wid] = ss;
    __syncthreads();
    if (t == 0) {
        float s = wsum[0] + wsum[1] + wsum[2] + wsum[3];
        invn[j] = 1.0f / fmaxf(sqrtf(s), 1e-12f);
    }
}

// ---------------- pre_acts GEMM: C = x @ W_enc + b_enc ----------------
// 128x128 tile, 8x8 per thread with SPLIT fragments ({base, base+64}) so b128 LDS
// reads/writes are <=2-way bank-aliased (free). Each C element keeps ONE fp32
// accumulator with an ascending-k fmaf chain (BLAS microkernel semantics) so
// near-tie rounding matches the fp32 reference and the top-k ranking agrees.
#define BM 128
#define BN 128
#define BK 16

__global__ __launch_bounds__(256) void gemm_preacts(const float* __restrict__ X,
                                                    const float* __restrict__ W,
                                                    const float* __restrict__ be,
                                                    float* __restrict__ C) {
    __shared__ float As[BK][BM + 4];  // k-major, m contiguous
    __shared__ float Bs[BK][BN];

    int tid = threadIdx.x;
    int tx = tid & 15, ty = tid >> 4;      // 16x16 thread grid
    int m0 = blockIdx.y * BM, n0 = blockIdx.x * BN;

    // A staging: rows ar and ar+64, k-offset ac (float4)
    int ar = tid >> 2;          // 0..63
    int ac = (tid & 3) * 4;     // 0,4,8,12
    // B staging: row bkr, cols bc and bc+64 (two float4, 2-way-bank writes)
    int bkr = tid >> 4;         // 0..15
    int bc = (tid & 15) * 4;    // 0..60

    float acc[8][8];
    #pragma unroll
    for (int i = 0; i < 8; ++i)
        #pragma unroll
        for (int j = 0; j < 8; ++j) acc[i][j] = 0.0f;

    for (int k0 = 0; k0 < 768; k0 += BK) {
        float4 av1 = *reinterpret_cast<const float4*>(X + (size_t)(m0 + ar) * 768 + k0 + ac);
        float4 av2 = *reinterpret_cast<const float4*>(X + (size_t)(m0 + 64 + ar) * 768 + k0 + ac);
        As[ac + 0][ar] = av1.x;  As[ac + 1][ar] = av1.y;
        As[ac + 2][ar] = av1.z;  As[ac + 3][ar] = av1.w;
        As[ac + 0][64 + ar] = av2.x;  As[ac + 1][64 + ar] = av2.y;
        As[ac + 2][64 + ar] = av2.z;  As[ac + 3][64 + ar] = av2.w;
        float4 bv1 = *reinterpret_cast<const float4*>(W + (size_t)(k0 + bkr) * D_SAE + n0 + bc);
        float4 bv2 = *reinterpret_cast<const float4*>(W + (size_t)(k0 + bkr) * D_SAE + n0 + 64 + bc);
        *reinterpret_cast<float4*>(&Bs[bkr][bc])      = bv1;
        *reinterpret_cast<float4*>(&Bs[bkr][64 + bc]) = bv2;
        __syncthreads();

        #pragma unroll
        for (int kk = 0; kk < BK; ++kk) {
            float4 a0 = *reinterpret_cast<const float4*>(&As[kk][ty * 4]);
            float4 a1 = *reinterpret_cast<const float4*>(&As[kk][64 + ty * 4]);
            float4 b0 = *reinterpret_cast<const float4*>(&Bs[kk][tx * 4]);
            float4 b1 = *reinterpret_cast<const float4*>(&Bs[kk][64 + tx * 4]);
            float aa[8] = {a0.x, a0.y, a0.z, a0.w, a1.x, a1.y, a1.z, a1.w};
            float bb[8] = {b0.x, b0.y, b0.z, b0.w, b1.x, b1.y, b1.z, b1.w};
            #pragma unroll
            for (int i = 0; i < 8; ++i)
                #pragma unroll
                for (int j = 0; j < 8; ++j)
                    acc[i][j] = fmaf(aa[i], bb[j], acc[i][j]);
        }
        __syncthreads();
    }

    float4 be0 = *reinterpret_cast<const float4*>(be + n0 + tx * 4);
    float4 be1 = *reinterpret_cast<const float4*>(be + n0 + 64 + tx * 4);
    float bbias[8] = {be0.x, be0.y, be0.z, be0.w, be1.x, be1.y, be1.z, be1.w};
    #pragma unroll
    for (int i = 0; i < 8; ++i) {
        int rowi = (i < 4) ? (ty * 4 + i) : (64 + ty * 4 + (i - 4));
        size_t row = (size_t)(m0 + rowi);
        float4 o0, o1;
        o0.x = acc[i][0] + bbias[0]; o0.y = acc[i][1] + bbias[1];
        o0.z = acc[i][2] + bbias[2]; o0.w = acc[i][3] + bbias[3];
        o1.x = acc[i][4] + bbias[4]; o1.y = acc[i][5] + bbias[5];
        o1.z = acc[i][6] + bbias[6]; o1.w = acc[i][7] + bbias[7];
        *reinterpret_cast<float4*>(C + row * D_SAE + n0 + tx * 4)      = o0;
        *reinterpret_cast<float4*>(C + row * D_SAE + n0 + 64 + tx * 4) = o1;
    }
}

// ---------------- exact top-64 via radix select + bitonic sort + header stash --------
__device__ inline unsigned int f2key(float f) {
    unsigned int u = __float_as_uint(f);
    return (u & 0x80000000u) ? ~u : (u | 0x80000000u);   // ascending uint == ascending float
}
__device__ inline float key2f(unsigned int u) {
    return (u & 0x80000000u) ? __uint_as_float(u & 0x7FFFFFFFu) : __uint_as_float(~u);
}

__global__ __launch_bounds__(256) void select_kernel(const float* __restrict__ invn,
                                                     float* __restrict__ lat) {
    __shared__ unsigned int us[D_SAE];
    __shared__ unsigned int hist[256];
    __shared__ unsigned long long skey[NCAP];
    __shared__ unsigned int prefix_s;
    __shared__ int rank_s, ncand_s;
    __shared__ float sv[64];
    __shared__ int si[64];

    int r = blockIdx.x, t = threadIdx.x;
    float* L = lat + (size_t)r * D_SAE;

    for (int i = t; i < D_SAE; i += 256) us[i] = f2key(L[i]);
    if (t == 0) { prefix_s = 0; rank_s = 64; ncand_s = 0; }
    __syncthreads();

    // ---- 4-pass radix select: exact 64th-largest key ----
    #pragma unroll
    for (int pass = 0; pass < 4; ++pass) {
        int shift = 24 - pass * 8;
        hist[t] = 0;
        __syncthreads();
        unsigned int pfx = prefix_s;
        for (int i = t; i < D_SAE; i += 256) {
            unsigned int u = us[i];
            bool in_group = (pass == 0) || ((u >> (shift + 8)) == pfx);
            if (in_group) atomicAdd(&hist[(u >> shift) & 255u], 1u);
        }
        __syncthreads();
        if (t == 0) {
            int rank = rank_s;
            unsigned int c = 0;
            for (int b = 255; b >= 0; --b) {
                unsigned int nc = c + hist[b];
                if ((int)nc >= rank) {
                    prefix_s = (prefix_s << 8) | (unsigned int)b;
                    rank_s = rank - (int)c;
                    break;
                }
                c = nc;
            }
        }
        __syncthreads();
    }
    unsigned int utau = prefix_s;   // key of the 64th-largest value

    // ---- gather all candidates >= utau ----
    for (int i = t; i < D_SAE; i += 256) {
        unsigned int u = us[i];
        if (u >= utau) {
            int p = atomicAdd(&ncand_s, 1);
            if (p < NCAP) skey[p] = (((unsigned long long)(~u)) << 32) | (unsigned int)i;
        }
    }
    __syncthreads();
    int n = ncand_s < NCAP ? ncand_s : NCAP;
    for (int p = n + t; p < NCAP; p += 256) skey[p] = 0xFFFFFFFFFFFFFFFFULL;
    __syncthreads();

    // ---- bitonic sort 128 slots ascending: (value desc, index asc) ----
    for (int k = 2; k <= NCAP; k <<= 1) {
        for (int j = k >> 1; j > 0; j >>= 1) {
            if (t < NCAP) {
                int ixj = t ^ j;
                if (ixj > t) {
                    unsigned long long a = skey[t], b = skey[ixj];
                    bool up = ((t & k) == 0);
                    if (up ? (a > b) : (a < b)) { skey[t] = b; skey[ixj] = a; }
                }
            }
            __syncthreads();
        }
    }

    // ---- main-32 + aux-32 (aux skips positive mains, re-admits non-positive mains) ----
    if (t == 0) {
        for (int j = 0; j < 32; ++j) {
            unsigned int u = ~(unsigned int)(skey[j] >> 32);
            si[j] = (int)(unsigned int)skey[j];
            sv[j] = key2f(u);
        }
        int cnt = 0;
        for (int c = 0; c < n && cnt < 32; ++c) {
            unsigned int u = ~(unsigned int)(skey[c] >> 32);
            float v = key2f(u);
            bool posmain = (c < 32) && (v > 0.0f);
            if (!posmain) {
                si[32 + cnt] = (int)(unsigned int)skey[c];
                sv[32 + cnt] = v;
                ++cnt;
            }
        }
    }
    __syncthreads();

    // header stash into the latents row (decode consumes & overwrites):
    // [0,64): indices (int bits); [64,96): relu(main vals); [96,160): decode scales
    if (t < 64) {
        L[t] = __int_as_float(si[t]);
    } else if (t < 96) {
        L[t] = fmaxf(sv[t - 64], 0.0f);
    } else if (t < 160) {
        int j = t - 96;
        L[t] = fmaxf(sv[j], 0.0f) * invn[si[j]];
    }
}

// ---------------- latents write + decode + losses ----------------
__global__ __launch_bounds__(256) void decode_kernel(const float* __restrict__ X,
                                                     const float* __restrict__ Wdec,
                                                     const float* __restrict__ bdec,
                                                     float* __restrict__ lat,
                                                     float* __restrict__ xhat,
                                                     float* __restrict__ lossp) {
    __shared__ int sib[64];
    __shared__ float lv[32];
    __shared__ float sc[64];

    int r = blockIdx.x, t = threadIdx.x;
    int lane = t & 63, wid = t >> 6;
    float* L = lat + (size_t)r * D_SAE;

    if (t < 64) sib[t] = __float_as_int(L[t]);
    else if (t < 96) lv[t - 64] = L[t];
    else if (t < 160) sc[t - 96] = L[t];
    __syncthreads();

    for (int i = t; i < D_SAE; i += 256) L[i] = 0.0f;
    __syncthreads();
    if (t < 32) L[sib[t]] = lv[t];

    int c0 = t, c1 = t + 256, c2 = t + 512;
    float xh0 = bdec[c0], xh1 = bdec[c1], xh2 = bdec[c2];
    #pragma unroll 4
    for (int j = 0; j < 32; ++j) {
        const float* w = Wdec + (size_t)sib[j] * D_MODEL;
        float v = sc[j];
        xh0 += v * w[c0]; xh1 += v * w[c1]; xh2 += v * w[c2];
    }
    float a0 = 0.f, a1 = 0.f, a2 = 0.f;
    #pragma unroll 4
    for (int j = 32; j < 64; ++j) {
        const float* w = Wdec + (size_t)sib[j] * D_MODEL;
        float v = sc[j];
        a0 += v * w[c0]; a1 += v * w[c1]; a2 += v * w[c2];
    }
    const float* xr = X + (size_t)r * D_MODEL;
    float xv0 = xr[c0], xv1 = xr[c1], xv2 = xr[c2];
    float* xo = xhat + (size_t)r * D_MODEL;
    xo[c0] = xh0; xo[c1] = xh1; xo[c2] = xh2;

    float d0 = xh0 - xv0, d1 = xh1 - xv1, d2 = xh2 - xv2;
    float lsum = d0 * d0 + d1 * d1 + d2 * d2;
    float e0 = a0 - (xv0 - xh0), e1 = a1 - (xv1 - xh1), e2 = a2 - (xv2 - xh2);
    float asum = e0 * e0 + e1 * e1 + e2 * e2;

    #pragma unroll
    for (int m = 32; m >= 1; m >>= 1) {
        lsum += __shfl_xor(lsum, m, 64);
        asum += __shfl_xor(asum, m, 64);
    }
    __shared__ float rl[4], ra[4];
    if (lane == 0) { rl[wid] = lsum; ra[wid] = asum; }
    __syncthreads();
    if (t == 0) {
        atomicAdd(&lossp[0], rl[0] + rl[1] + rl[2] + rl[3]);
        atomicAdd(&lossp[1], ra[0] + ra[1] + ra[2] + ra[3]);
    }
}

// ---------------- final scalars ----------------
__global__ void finish_kernel(float* __restrict__ lossp) {
    const double inv = 1.0 / (double)((size_t)BATCH * D_MODEL);
    if (threadIdx.x == 0) {
        lossp[0] = (float)((double)lossp[0] * inv);
        lossp[1] = (float)((double)lossp[1] * inv * (1.0 / 32.0));
    }
}

extern "C" void kernel_launch(void* const* d_in, const int* in_sizes, int n_in,
                              void* d_out, int out_size, void* d_ws, size_t ws_size,
                              hipStream_t stream) {
    const float* x     = (const float*)d_in[0];
    const float* W_enc = (const float*)d_in[1];
    const float* b_enc = (const float*)d_in[2];
    const float* W_dec = (const float*)d_in[3];
    const float* b_dec = (const float*)d_in[4];

    float* out = (float*)d_out;
    float* xhat  = out + XHAT_OFF;
    float* lat   = out + LAT_OFF;
    float* lossp = out + LOSS_OFF;
    float* invn  = xhat;   // first 6144 floats of xhat region; consumed before xhat write

    hipLaunchKernelGGL(init_loss, dim3(1), dim3(64), 0, stream, lossp);
    hipLaunchKernelGGL(rownorm_kernel, dim3(D_SAE), dim3(256), 0, stream, W_dec, invn);
    hipLaunchKernelGGL(gemm_preacts, dim3(D_SAE / BN, BATCH / BM), dim3(256), 0, stream,
                       x, W_enc, b_enc, lat);
    hipLaunchKernelGGL(select_kernel, dim3(BATCH), dim3(256), 0, stream, invn, lat);
    hipLaunchKernelGGL(decode_kernel, dim3(BATCH), dim3(256), 0, stream,
                       x, W_dec, b_dec, lat, xhat, lossp);
    hipLaunchKernelGGL(finish_kernel, dim3(1), dim3(1), 0, stream, lossp);
}